// Round 1
// baseline (106405.615 us; speedup 1.0000x reference)
//
#include <hip/hip_runtime.h>
#include <hip/hip_bf16.h>
#include <math.h>
#include <stddef.h>

#define B   32
#define TE  400
#define TD  800
#define ED  512
#define DD  80
#define LS  1024
#define G4  4096
#define UN  128
#define FLT 32
#define KW  31
#define KSPLIT 16

__device__ __forceinline__ float fsig(float x){ return 1.f/(1.f+__expf(-x)); }
__device__ __forceinline__ float ftanh(float x){ return 1.f - 2.f/(__expf(2.f*x)+1.f); }

// keys = values @ Wm : [B, TE, UN]
__global__ void keys_kernel(const float* __restrict__ values, const float* __restrict__ Wm,
                            float* __restrict__ keys)
{
    int b  = blockIdx.x;      // 0..31
    int tg = blockIdx.y;      // 0..49 (groups of 8 t_enc rows)
    int tid = threadIdx.x;    // 128
    __shared__ __align__(16) float v[8*512];
    const float* vb = values + (size_t)b*TE*ED + (size_t)tg*8*ED;
    for (int i = tid; i < 8*512; i += 128) v[i] = vb[i];
    __syncthreads();
    int u = tid;
    float acc[8];
#pragma unroll
    for (int i=0;i<8;i++) acc[i]=0.f;
    for (int k=0;k<ED;k++){
        float w = Wm[k*UN + u];
#pragma unroll
        for (int tt=0; tt<8; tt++) acc[tt] += v[tt*512 + k]*w;
    }
#pragma unroll
    for (int tt=0; tt<8; tt++)
        keys[(size_t)b*TE*UN + (size_t)(tg*8+tt)*UN + u] = acc[tt];
}

// z0 partials: [x(dec_t, c_prev) ; h0] @ [W0 ; U0] ; K = 80+512+1024 = 1616 = 16*101
__global__ void lstm_gemm_a(int t, const float* __restrict__ dec,
                            const float* __restrict__ c_out,
                            const float* __restrict__ h0,
                            const float* __restrict__ W0, const float* __restrict__ U0,
                            float* __restrict__ zbuf)
{
    const int KC = 101;
    int nx = blockIdx.x;      // 0..15 (n-tile of 256)
    int ky = blockIdx.y;      // 0..15 (k-chunk)
    int tid = threadIdx.x;    // 256
    int n  = nx*256 + tid;
    int k0 = ky*KC;
    __shared__ __align__(16) float xh[KC*32];
    for (int i = tid; i < KC*32; i += 256){
        int kk = i >> 5; int b = i & 31;
        int k = k0 + kk;
        float v;
        if (k < DD)           v = dec[(size_t)b*TD*DD + (size_t)t*DD + k];
        else if (k < DD+ED)   v = (t==0) ? 0.f
                                  : c_out[(size_t)b*TD*ED + (size_t)(t-1)*ED + (k-DD)];
        else                  v = h0[b*LS + (k-(DD+ED))];
        xh[i] = v;
    }
    __syncthreads();
    float acc[32];
#pragma unroll
    for (int i=0;i<32;i++) acc[i]=0.f;
    for (int kk=0; kk<KC; kk++){
        int k = k0 + kk;
        float w = (k < DD+ED) ? W0[(size_t)k*G4 + n]
                              : U0[(size_t)(k-(DD+ED))*G4 + n];
        const float4* xr = (const float4*)&xh[kk*32];
#pragma unroll
        for (int i=0;i<8;i++){
            float4 x4 = xr[i];
            acc[4*i+0] += x4.x*w;
            acc[4*i+1] += x4.y*w;
            acc[4*i+2] += x4.z*w;
            acc[4*i+3] += x4.w*w;
        }
    }
    float* zb = zbuf + (size_t)ky*B*G4;
#pragma unroll
    for (int b=0;b<32;b++) zb[b*G4 + n] = acc[b];
}

// z1 partials: [h0 ; h1] @ [W1 ; U1] ; K = 2048 = 16*128
__global__ void lstm_gemm_b(const float* __restrict__ h0,
                            const float* __restrict__ h1,
                            const float* __restrict__ W1, const float* __restrict__ U1,
                            float* __restrict__ zbuf)
{
    const int KC = 128;
    int nx = blockIdx.x; int ky = blockIdx.y; int tid = threadIdx.x;
    int n  = nx*256 + tid;
    int k0 = ky*KC;
    __shared__ __align__(16) float xh[KC*32];
    for (int i = tid; i < KC*32; i += 256){
        int kk = i >> 5; int b = i & 31;
        int k = k0 + kk;
        xh[i] = (k < LS) ? h0[b*LS + k] : h1[b*LS + (k-LS)];
    }
    __syncthreads();
    float acc[32];
#pragma unroll
    for (int i=0;i<32;i++) acc[i]=0.f;
    for (int kk=0; kk<KC; kk++){
        int k = k0 + kk;
        float w = (k < LS) ? W1[(size_t)k*G4 + n] : U1[(size_t)(k-LS)*G4 + n];
        const float4* xr = (const float4*)&xh[kk*32];
#pragma unroll
        for (int i=0;i<8;i++){
            float4 x4 = xr[i];
            acc[4*i+0] += x4.x*w;
            acc[4*i+1] += x4.y*w;
            acc[4*i+2] += x4.z*w;
            acc[4*i+3] += x4.w*w;
        }
    }
    float* zb = zbuf + (size_t)ky*B*G4;
#pragma unroll
    for (int b=0;b<32;b++) zb[b*G4 + n] = acc[b];
}

// sum k-split partials + bias, apply LSTM gates (Keras order i,f,g,o)
__global__ void lstm_gate(const float* __restrict__ zbuf, const float* __restrict__ bias,
                          float* __restrict__ h, float* __restrict__ c,
                          float* __restrict__ denom)
{
    int idx = blockIdx.x*256 + threadIdx.x;   // 0..32767 ; b = idx>>10, j = idx&1023
    int b = idx >> 10; int j = idx & 1023;
    float zs[4];
#pragma unroll
    for (int g=0; g<4; g++){
        int col = j + g*1024;
        float s = bias[col];
#pragma unroll
        for (int sp=0; sp<KSPLIT; sp++)
            s += zbuf[(size_t)sp*B*G4 + (size_t)b*G4 + col];
        zs[g] = s;
    }
    float cn = fsig(zs[1])*c[idx] + fsig(zs[0])*ftanh(zs[2]);
    float hn = fsig(zs[3])*ftanh(cn);
    c[idx] = cn; h[idx] = hn;
    if (denom != nullptr && idx < B) denom[idx] = 0.f;
}

// conv(prev_align) -> loc ; pq = h1@Wq ; e = sum v_a*tanh(keys+pq+loc+b_a) ; exp(e)
__global__ void attn_energy(int t, const float* __restrict__ h1,
                            const float* __restrict__ Wq,
                            const float* __restrict__ keysb,
                            const float* __restrict__ align,
                            const float* __restrict__ convk, const float* __restrict__ convb,
                            const float* __restrict__ Wloc,
                            const float* __restrict__ v_a, const float* __restrict__ b_a,
                            float* __restrict__ e_out, float* __restrict__ denom)
{
    int chunk = blockIdx.x;   // 0..7  -> 50 t_enc positions
    int b = blockIdx.y;
    int t0 = chunk*50;
    int tid = threadIdx.x;    // 256
    __shared__ float pq[UN];
    __shared__ float aw[80];
    __shared__ float fls[50*FLT];
    __shared__ float elds[50*129];
    __shared__ float psum[50];

    if (tid < UN){
        int u = tid;
        float s = b_a[u];
        const float* hr = h1 + b*LS;
        for (int k=0; k<LS; k+=4){
            s += hr[k+0]*Wq[(k+0)*UN+u];
            s += hr[k+1]*Wq[(k+1)*UN+u];
            s += hr[k+2]*Wq[(k+2)*UN+u];
            s += hr[k+3]*Wq[(k+3)*UN+u];
        }
        pq[u] = s;
    } else if (tid < UN+80){
        int j = tid - UN;
        int p = t0 + j - 15;
        aw[j] = (p >= 0 && p < TE) ? align[b*TE + p] : 0.f;
    }
    __syncthreads();
    // conv: 50 positions x 32 filters
    for (int o = tid; o < 50*FLT; o += 256){
        int pos = o >> 5, fl = o & 31;
        float s = convb[fl];
#pragma unroll
        for (int k=0; k<KW; k++) s += aw[pos+k]*convk[k*FLT + fl];
        fls[o] = s;
    }
    __syncthreads();
    const float* kb = keysb + (size_t)b*TE*UN + (size_t)t0*UN;
    for (int o = tid; o < 50*UN; o += 256){
        int pos = o >> 7, u = o & 127;
        float loc = 0.f;
        const float* fr = &fls[pos*FLT];
#pragma unroll
        for (int fl=0; fl<FLT; fl++) loc += fr[fl]*Wloc[fl*UN + u];
        float x = kb[pos*UN + u] + pq[u] + loc;   // b_a already folded into pq
        elds[pos*129 + u] = v_a[u]*ftanh(x);
    }
    __syncthreads();
    if (tid < 50){
        int pos = tid;
        float e = 0.f;
        for (int u=0; u<UN; u++) e += elds[pos*129 + u];
        float ex = __expf(e);   // |e| <= sum|v_a| ~ 5 : max-free softmax is safe
        e_out[(size_t)b*TD*TE + (size_t)t*TE + t0 + pos] = ex;
        psum[pos] = ex;
    }
    __syncthreads();
    if (tid == 0){
        float s = 0.f;
        for (int p=0; p<50; p++) s += psum[p];
        atomicAdd(&denom[b], s);
    }
}

// normalize a, accumulate cumulative alignment, compute context -> c_out row t
__global__ void attn_ctx(int t, const float* __restrict__ values,
                         const float* __restrict__ denom,
                         float* __restrict__ e_out, float* __restrict__ align,
                         float* __restrict__ c_out)
{
    int chunk = blockIdx.x; int b = blockIdx.y;
    int t0 = chunk*50; int tid = threadIdx.x;
    __shared__ float alds[50];
    if (tid < 50){
        size_t ei = (size_t)b*TD*TE + (size_t)t*TE + t0 + tid;
        float a = e_out[ei] / denom[b];
        e_out[ei] = a;
        align[b*TE + t0 + tid] += a;
        alds[tid] = a;
    }
    __syncthreads();
    const float* vb = values + (size_t)b*TE*ED + (size_t)t0*ED;
    float* cr = c_out + (size_t)b*TD*ED + (size_t)t*ED;
    for (int d = tid; d < ED; d += 256){
        float acc = 0.f;
#pragma unroll 10
        for (int p=0; p<50; p++) acc += alds[p]*vb[p*ED + d];
        atomicAdd(&cr[d], acc);
    }
}

extern "C" void kernel_launch(void* const* d_in, const int* in_sizes, int n_in,
                              void* d_out, int out_size, void* d_ws, size_t ws_size,
                              hipStream_t stream)
{
    const float* enc   = (const float*)d_in[0];
    const float* dec   = (const float*)d_in[1];
    const float* Wm    = (const float*)d_in[2];
    const float* Wq    = (const float*)d_in[3];
    const float* convk = (const float*)d_in[4];
    const float* convb = (const float*)d_in[5];
    const float* Wloc  = (const float*)d_in[6];
    const float* v_a   = (const float*)d_in[7];
    const float* b_a   = (const float*)d_in[8];
    const float* W0    = (const float*)d_in[9];
    const float* U0    = (const float*)d_in[10];
    const float* b0    = (const float*)d_in[11];
    const float* W1    = (const float*)d_in[12];
    const float* U1    = (const float*)d_in[13];
    const float* b1    = (const float*)d_in[14];

    float* out   = (float*)d_out;
    float* c_out = out;                                  // [B, TD, ED]
    float* e_out = out + (size_t)B*TD*ED;                // [B, TD, TE]

    float* ws    = (float*)d_ws;
    float* h0    = ws;
    float* c0    = h0 + B*LS;
    float* h1    = c0 + B*LS;
    float* c1    = h1 + B*LS;
    float* align = c1 + B*LS;
    float* denom = align + B*TE;
    float* keys  = denom + B;
    float* zbuf0 = keys  + (size_t)B*TE*UN;
    float* zbuf1 = zbuf0 + (size_t)KSPLIT*B*G4;

    // zero LSTM state + alignment + denom (ws is poisoned before every call)
    hipMemsetAsync(ws, 0, (size_t)(4*B*LS + B*TE + B)*sizeof(float), stream);
    // zero context output region (accumulated via atomicAdd)
    hipMemsetAsync(c_out, 0, (size_t)B*TD*ED*sizeof(float), stream);

    keys_kernel<<<dim3(B,50), 128, 0, stream>>>(enc, Wm, keys);

    for (int t=0; t<TD; t++){
        lstm_gemm_a<<<dim3(16,16), 256, 0, stream>>>(t, dec, c_out, h0, W0, U0, zbuf0);
        lstm_gate  <<<128, 256, 0, stream>>>(zbuf0, b0, h0, c0, denom);
        lstm_gemm_b<<<dim3(16,16), 256, 0, stream>>>(h0, h1, W1, U1, zbuf1);
        lstm_gate  <<<128, 256, 0, stream>>>(zbuf1, b1, h1, c1, nullptr);
        attn_energy<<<dim3(8,B), 256, 0, stream>>>(t, h1, Wq, keys, align,
                                                   convk, convb, Wloc, v_a, b_a,
                                                   e_out, denom);
        attn_ctx   <<<dim3(8,B), 256, 0, stream>>>(t, enc, denom, e_out, align, c_out);
    }
}